// Round 1
// baseline (920.955 us; speedup 1.0000x reference)
//
#include <hip/hip_runtime.h>
#include <hip/hip_bf16.h>

// Problem constants
// B=64, C=32, V=1024, L=12, C_OUT=64, C_CAT=224
// M (prop GEMM rows) = B*C*L = 24576;  S = M*V = 25,165,824 elements per buffer
#define SBUF 25165824L

typedef __attribute__((ext_vector_type(4))) float  f32x4;
typedef __attribute__((ext_vector_type(8))) short  s16x8;
typedef __attribute__((ext_vector_type(4))) short  s16x4;

__device__ inline short f2bf(float f) {
    unsigned u = __builtin_bit_cast(unsigned, f);
    unsigned r = (u + 0x7FFFu + ((u >> 16) & 1u)) >> 16;   // round-to-nearest-even
    return (short)r;
}

__device__ inline f32x4 mfma16(s16x8 a, s16x8 b, f32x4 c) {
    return __builtin_amdgcn_mfma_f32_16x16x32_bf16(a, b, c, 0, 0, 0);
}

__device__ inline void gll16(const void* g, void* l) {
    __builtin_amdgcn_global_load_lds(
        (const __attribute__((address_space(1))) void*)g,
        (__attribute__((address_space(3))) void*)l, 16, 0, 0);
}

// ---------------------------------------------------------------------------
// x [B,C,V,L] fp32  ->  Xg bf16 [(b*C+c)*L + l][v]   (k=v contiguous)
// one thread: 8 consecutive v for one m
__global__ __launch_bounds__(256) void cast_x_kernel(const float* __restrict__ x,
                                                     short* __restrict__ Xg) {
    int idx = blockIdx.x * 256 + threadIdx.x;   // 3,145,728 total
    int m  = idx >> 7;
    int v0 = (idx & 127) << 3;
    int bc = m / 12;
    int l  = m - bc * 12;
    const float* src = x + (size_t)bc * 12288 + (size_t)v0 * 12 + l;
    s16x8 o;
#pragma unroll
    for (int i = 0; i < 8; ++i) o[i] = f2bf(src[i * 12]);
    *(s16x8*)(Xg + (size_t)m * 1024 + v0) = o;
}

// ---------------------------------------------------------------------------
// A_j [v][w] fp32 -> At_j bf16 [w][v]  (transpose + cast), 32x32 LDS tiles
__global__ __launch_bounds__(256) void cast_a_kernel(const float* __restrict__ a0,
                                                     const float* __restrict__ a1,
                                                     const float* __restrict__ a2,
                                                     short* __restrict__ At) {
    __shared__ float t[32][33];
    int z = blockIdx.z;
    const float* A = (z == 0) ? a0 : ((z == 1) ? a1 : a2);
    int v0 = blockIdx.x * 32;
    int w0 = blockIdx.y * 32;
    int tr = threadIdx.x >> 3;
    int tc = (threadIdx.x & 7) << 2;
    float4 val = *(const float4*)&A[(size_t)(v0 + tr) * 1024 + w0 + tc];
    t[tr][tc + 0] = val.x; t[tr][tc + 1] = val.y;
    t[tr][tc + 2] = val.z; t[tr][tc + 3] = val.w;
    __syncthreads();
    s16x4 o;
#pragma unroll
    for (int i = 0; i < 4; ++i) o[i] = f2bf(t[tc + i][tr]);
    *(s16x4*)(At + (size_t)z * 1048576 + (size_t)(w0 + tr) * 1024 + v0 + tc) = o;
}

// ---------------------------------------------------------------------------
// Prop GEMM:  C[m,w] = sum_v X[m,v] * At[w,v]     (X: M x 1024, At: 1024 x 1024)
// 128x128 tile, BK=32, 4 waves (2x2), 16 MFMAs/wave/K-step, global_load_lds x16.
// Outputs: Cmv (optional, [m][w] bf16)  and  Cxl (x-layout bf16: [bc][w*12+l]).
__global__ __launch_bounds__(256, 2) void gemm_prop(const short* __restrict__ Xb,
                                                    long xzstride,
                                                    const short* __restrict__ Atb,
                                                    short* __restrict__ Cmvb,
                                                    short* __restrict__ Cxlb,
                                                    long cxlzstride) {
    __shared__ __align__(16) short Alds[128 * 32];
    __shared__ __align__(16) short Blds[128 * 32];

    const int tid  = threadIdx.x;
    const int lane = tid & 63;
    const int wid  = tid >> 6;
    const int wm   = wid >> 1;
    const int wn   = wid & 1;
    const int z    = blockIdx.z;
    const int m0   = blockIdx.y * 128;
    const int n0   = blockIdx.x * 128;

    const short* X  = Xb  + (size_t)z * xzstride;
    const short* At = Atb + (size_t)z * 1048576;
    short* Cmv = Cmvb ? (Cmvb + (size_t)z * SBUF) : nullptr;
    short* Cxl = Cxlb + (size_t)z * cxlzstride;

    // staging addresses: wave wid covers rows [wid*32, wid*32+32) of the tile
    const short* Ag = X  + (size_t)(m0 + wid * 32 + (lane >> 2)) * 1024 + (lane & 3) * 8;
    const short* Bg = At + (size_t)(n0 + wid * 32 + (lane >> 2)) * 1024 + (lane & 3) * 8;
    short* la = &Alds[wid * 1024];
    short* lb = &Blds[wid * 1024];

    const int lane15 = lane & 15;
    const int lq     = lane >> 4;
    const int ar     = lane15 * 32 + lq * 8;

    f32x4 acc[4][4] = {};

    for (int k0 = 0; k0 < 1024; k0 += 32) {
        __syncthreads();
        gll16(Ag + k0, la);
        gll16(Ag + k0 + 16 * 1024, la + 512);
        gll16(Bg + k0, lb);
        gll16(Bg + k0 + 16 * 1024, lb + 512);
        __syncthreads();

        s16x8 af[4], bf[4];
#pragma unroll
        for (int i = 0; i < 4; ++i)
            af[i] = *(const s16x8*)&Alds[(wm * 64 + i * 16) * 32 + ar];
#pragma unroll
        for (int j = 0; j < 4; ++j)
            bf[j] = *(const s16x8*)&Blds[(wn * 64 + j * 16) * 32 + ar];
#pragma unroll
        for (int i = 0; i < 4; ++i)
#pragma unroll
            for (int j = 0; j < 4; ++j)
                acc[i][j] = mfma16(af[i], bf[j], acc[i][j]);
    }

    // epilogue: D row = m index, D col = n index (col=lane&15, row=lq*4+reg)
#pragma unroll
    for (int i = 0; i < 4; ++i) {
        int rbase = m0 + wm * 64 + i * 16 + lq * 4;
#pragma unroll
        for (int r = 0; r < 4; ++r) {
            int row = rbase + r;
            int bc  = row / 12;
            int l   = row - bc * 12;
            size_t xlrow = (size_t)bc * 12288 + l;
#pragma unroll
            for (int j = 0; j < 4; ++j) {
                int col = n0 + wn * 64 + j * 16 + lane15;
                short v = f2bf(acc[i][j][r]);
                if (Cmv) Cmv[(size_t)row * 1024 + col] = v;
                Cxl[xlrow + (size_t)col * 12] = v;
            }
        }
    }
}

// ---------------------------------------------------------------------------
// Final 1x1 conv:  out[n,o,p] = b[o] + sum_{g,c} W[o, g*32+c] * H_g[n*32+c, p]
// per block: one n, 256 p columns, all 64 o.  K = 7 groups x 32.
// W staged once in LDS (padded stride 232); H-tile transpose-staged to [p][c].
__global__ __launch_bounds__(256, 2) void final_gemm(const float* __restrict__ x,
                                                     const short* __restrict__ Hxl,
                                                     const float* __restrict__ W,
                                                     const float* __restrict__ bias,
                                                     float* __restrict__ out) {
    __shared__ __align__(16) short Wlds[64 * 232];    // [o][c] stride 232
    __shared__ __align__(16) short Hlds[256 * 40];    // [p][c] stride 40

    const int tid  = threadIdx.x;
    const int lane = tid & 63;
    const int wv   = tid >> 6;
    const int n    = blockIdx.y;
    const int p0   = blockIdx.x * 256;
    const int lane15 = lane & 15;
    const int lq     = lane >> 4;

    // stage W (64x224 fp32 -> bf16), 14336 floats = 3584 float4, 14 per thread
#pragma unroll
    for (int it = 0; it < 14; ++it) {
        int i  = it * 256 + tid;
        int o  = i / 56;
        int c4 = (i - o * 56) * 4;
        float4 wval = *(const float4*)&W[(size_t)o * 224 + c4];
        Wlds[o * 232 + c4 + 0] = f2bf(wval.x);
        Wlds[o * 232 + c4 + 1] = f2bf(wval.y);
        Wlds[o * 232 + c4 + 2] = f2bf(wval.z);
        Wlds[o * 232 + c4 + 3] = f2bf(wval.w);
    }

    f32x4 acc[4][4] = {};
    const int c = tid & 31;
    const int q = tid >> 5;

    for (int g = 0; g < 7; ++g) {
        __syncthreads();
        if (g == 0) {
            const float* src = x + (size_t)(n * 32 + c) * 12288 + p0;
#pragma unroll
            for (int r = 0; r < 8; ++r) {
                int chunk = r * 8 + q;                 // 0..63, 4 p each
                float4 v = *(const float4*)&src[chunk * 4];
                int pb = chunk * 4;
                Hlds[(pb + 0) * 40 + c] = f2bf(v.x);
                Hlds[(pb + 1) * 40 + c] = f2bf(v.y);
                Hlds[(pb + 2) * 40 + c] = f2bf(v.z);
                Hlds[(pb + 3) * 40 + c] = f2bf(v.w);
            }
        } else {
            const short* src = Hxl + (size_t)(g - 1) * SBUF + (size_t)(n * 32 + c) * 12288 + p0;
#pragma unroll
            for (int r = 0; r < 4; ++r) {
                int chunk = r * 8 + q;                 // 0..31, 8 p each
                s16x8 v = *(const s16x8*)&src[chunk * 8];
                int pb = chunk * 8;
#pragma unroll
                for (int i = 0; i < 8; ++i) Hlds[(pb + i) * 40 + c] = v[i];
            }
        }
        __syncthreads();

        s16x8 afr[4], bfr[4];
#pragma unroll
        for (int ot = 0; ot < 4; ++ot)
            afr[ot] = *(const s16x8*)&Wlds[(ot * 16 + lane15) * 232 + g * 32 + lq * 8];
#pragma unroll
        for (int bt = 0; bt < 4; ++bt)
            bfr[bt] = *(const s16x8*)&Hlds[(wv * 64 + bt * 16 + lane15) * 40 + lq * 8];
#pragma unroll
        for (int ot = 0; ot < 4; ++ot)
#pragma unroll
            for (int bt = 0; bt < 4; ++bt)
                acc[ot][bt] = mfma16(afr[ot], bfr[bt], acc[ot][bt]);
    }

    // epilogue: rows = o, cols = p
#pragma unroll
    for (int ot = 0; ot < 4; ++ot) {
#pragma unroll
        for (int r = 0; r < 4; ++r) {
            int o = ot * 16 + lq * 4 + r;
            float bo = bias[o];
            size_t obase = ((size_t)n * 64 + o) * 12288 + p0;
#pragma unroll
            for (int bt = 0; bt < 4; ++bt) {
                int p = wv * 64 + bt * 16 + lane15;
                out[obase + p] = acc[ot][bt][r] + bo;
            }
        }
    }
}

// ---------------------------------------------------------------------------
extern "C" void kernel_launch(void* const* d_in, const int* in_sizes, int n_in,
                              void* d_out, int out_size, void* d_ws, size_t ws_size,
                              hipStream_t stream) {
    const float* x  = (const float*)d_in[0];
    const float* a0 = (const float*)d_in[1];
    const float* a1 = (const float*)d_in[2];
    const float* a2 = (const float*)d_in[3];
    const float* W  = (const float*)d_in[4];
    const float* bs = (const float*)d_in[5];
    float* out = (float*)d_out;

    // workspace layout (bytes):
    //   Xg   bf16 [24576][1024]            @ 0          50,331,648
    //   At   bf16 [3][1024][1024] (A^T)    @ 50331648    6,291,456
    //   X1mv bf16 [3][24576][1024]         @ 56623104  150,994,944
    //   Hxl  bf16 [6][2048][12288]         @ 207618048 301,989,888
    // total ~486 MiB
    char* ws = (char*)d_ws;
    short* Xg   = (short*)(ws);
    short* At   = (short*)(ws + 50331648L);
    short* X1mv = (short*)(ws + 56623104L);
    short* Hxl  = (short*)(ws + 207618048L);

    cast_x_kernel<<<12288, 256, 0, stream>>>(x, Xg);
    cast_a_kernel<<<dim3(32, 32, 3), 256, 0, stream>>>(a0, a1, a2, At);

    // order-1: X1_j = Xg @ A_j   (dual write: [m,v] + x-layout slot 2j)
    gemm_prop<<<dim3(8, 192, 3), 256, 0, stream>>>(Xg, 0L, At, X1mv, Hxl, 2 * SBUF);
    // order-2: X2_j = X1_j @ A_j (x-layout slot 2j+1 only)
    gemm_prop<<<dim3(8, 192, 3), 256, 0, stream>>>(X1mv, SBUF, At, nullptr, Hxl + SBUF, 2 * SBUF);

    final_gemm<<<dim3(48, 64), 256, 0, stream>>>(x, Hxl, W, bs, out);
}

// Round 2
// 847.762 us; speedup vs baseline: 1.0863x; 1.0863x over previous
//
#include <hip/hip_runtime.h>
#include <hip/hip_bf16.h>

// B=64, C=32, V=1024, L=12, C_OUT=64, C_CAT=224
// M = B*C*L = 24576 rows; N = 6 slices * 1024 = 6144 cols; K = 1024.
// Slice order s: 0=A0^T, 1=(A0^2)^T, 2=A1^T, 3=(A1^2)^T, 4=A2^T, 5=(A2^2)^T
// so H group g (1..6) in the final conv = slice s = g-1 (matches ref concat).

typedef __attribute__((ext_vector_type(4))) float  f32x4;
typedef __attribute__((ext_vector_type(8))) short  s16x8;
typedef __attribute__((ext_vector_type(4))) short  s16x4;

__device__ inline short f2bf(float f) {
    unsigned u = __builtin_bit_cast(unsigned, f);
    unsigned r = (u + 0x7FFFu + ((u >> 16) & 1u)) >> 16;   // RNE
    return (short)r;
}

__device__ inline f32x4 mfma16(s16x8 a, s16x8 b, f32x4 c) {
    return __builtin_amdgcn_mfma_f32_16x16x32_bf16(a, b, c, 0, 0, 0);
}

__device__ inline void gll16(const void* g, void* l) {
    __builtin_amdgcn_global_load_lds(
        (const __attribute__((address_space(1))) void*)g,
        (__attribute__((address_space(3))) void*)l, 16, 0, 0);
}

// ---------------------------------------------------------------------------
// x [B,C,V,L] fp32 -> Xg bf16 [(bc)*12 + l][v].  One block per bc slab.
// Coalesced float4 reads, LDS transpose ([l][v] stride 1040), coalesced stores.
__global__ __launch_bounds__(256) void cast_x_v2(const float* __restrict__ x,
                                                 short* __restrict__ Xg) {
    __shared__ short Xl[12 * 1040];
    const int bc = blockIdx.x;
    const int t  = threadIdx.x;
    const float4* src = (const float4*)(x + (size_t)bc * 12288);
#pragma unroll
    for (int k = 0; k < 12; ++k) {
        int f4 = k * 256 + t;                 // 0..3071
        float4 v = src[f4];
        int f  = f4 * 4;
        int vi = f / 12;
        int li = f - vi * 12;
        float vals[4] = {v.x, v.y, v.z, v.w};
#pragma unroll
        for (int e = 0; e < 4; ++e) {
            Xl[li * 1040 + vi] = f2bf(vals[e]);
            if (++li == 12) { li = 0; ++vi; }
        }
    }
    __syncthreads();
#pragma unroll
    for (int k = 0; k < 6; ++k) {
        int ch = k * 256 + t;                 // 0..1535
        int l  = ch >> 7;
        int v8 = ch & 127;
        *(s16x8*)(Xg + ((size_t)bc * 12 + l) * 1024 + v8 * 8) =
            *(const s16x8*)&Xl[l * 1040 + v8 * 8];
    }
}

// ---------------------------------------------------------------------------
// A_j [v][w] fp32 -> At_j bf16 [w][v] (into Bt_all slice 2j)  +  Ab_j bf16 [v][w]
__global__ __launch_bounds__(256) void cast_a_v2(const float* __restrict__ a0,
                                                 const float* __restrict__ a1,
                                                 const float* __restrict__ a2,
                                                 short* __restrict__ Btall,
                                                 short* __restrict__ Ab) {
    __shared__ float tbuf[32][33];
    const int z = blockIdx.z;
    const float* A = (z == 0) ? a0 : ((z == 1) ? a1 : a2);
    const int v0 = blockIdx.x * 32;
    const int w0 = blockIdx.y * 32;
    const int tr = threadIdx.x >> 3;
    const int tc = (threadIdx.x & 7) << 2;
    float4 val = *(const float4*)&A[(size_t)(v0 + tr) * 1024 + w0 + tc];
    // straight cast (Ab)
    s16x4 sb;
    sb[0] = f2bf(val.x); sb[1] = f2bf(val.y); sb[2] = f2bf(val.z); sb[3] = f2bf(val.w);
    *(s16x4*)(Ab + (size_t)z * 1048576 + (size_t)(v0 + tr) * 1024 + w0 + tc) = sb;
    // transpose via LDS (At into Bt_all slice 2z)
    tbuf[tr][tc + 0] = val.x; tbuf[tr][tc + 1] = val.y;
    tbuf[tr][tc + 2] = val.z; tbuf[tr][tc + 3] = val.w;
    __syncthreads();
    s16x4 st;
#pragma unroll
    for (int i = 0; i < 4; ++i) st[i] = f2bf(tbuf[tc + i][tr]);
    *(s16x4*)(Btall + (size_t)(2 * z) * 1048576 + (size_t)(w0 + tr) * 1024 + v0 + tc) = st;
}

// ---------------------------------------------------------------------------
// BT-GEMM: C[m][n] = sum_k X[m][k] * Bt[n][k], K = 1024 fixed.
// 128x128 tile, BK=32, 4 waves (2x2), global_load_lds width 16 (m97 structure).
__global__ __launch_bounds__(256, 2) void gemm_bt(const short* __restrict__ Xb, long xz,
                                                  const short* __restrict__ Btb, long bz,
                                                  short* __restrict__ Cb, long cz,
                                                  int crow) {
    __shared__ __align__(16) short Alds[128 * 32];
    __shared__ __align__(16) short Blds[128 * 32];

    const int tid  = threadIdx.x;
    const int lane = tid & 63;
    const int wid  = tid >> 6;
    const int wm   = wid >> 1;
    const int wn   = wid & 1;
    const int m0   = blockIdx.y * 128;
    const int n0   = blockIdx.x * 128;

    const short* X  = Xb  + (size_t)blockIdx.z * xz;
    const short* Bt = Btb + (size_t)blockIdx.z * bz;
    short*       C  = Cb  + (size_t)blockIdx.z * cz;

    const short* Ag = X  + (size_t)(m0 + wid * 32 + (lane >> 2)) * 1024 + (lane & 3) * 8;
    const short* Bg = Bt + (size_t)(n0 + wid * 32 + (lane >> 2)) * 1024 + (lane & 3) * 8;
    short* la = &Alds[wid * 1024];
    short* lb = &Blds[wid * 1024];

    const int lane15 = lane & 15;
    const int lq     = lane >> 4;
    const int ar     = lane15 * 32 + lq * 8;

    f32x4 acc[4][4] = {};

    for (int k0 = 0; k0 < 1024; k0 += 32) {
        __syncthreads();
        gll16(Ag + k0, la);
        gll16(Ag + k0 + 16 * 1024, la + 512);
        gll16(Bg + k0, lb);
        gll16(Bg + k0 + 16 * 1024, lb + 512);
        __syncthreads();

        s16x8 af[4], bf[4];
#pragma unroll
        for (int i = 0; i < 4; ++i)
            af[i] = *(const s16x8*)&Alds[(wm * 64 + i * 16) * 32 + ar];
#pragma unroll
        for (int j = 0; j < 4; ++j)
            bf[j] = *(const s16x8*)&Blds[(wn * 64 + j * 16) * 32 + ar];
#pragma unroll
        for (int i = 0; i < 4; ++i)
#pragma unroll
            for (int j = 0; j < 4; ++j)
                acc[i][j] = mfma16(af[i], bf[j], acc[i][j]);
    }

    // epilogue: D col = lane&15, row = lq*4 + reg; plain row-major store
#pragma unroll
    for (int i = 0; i < 4; ++i) {
        int rbase = m0 + wm * 64 + i * 16 + lq * 4;
#pragma unroll
        for (int r = 0; r < 4; ++r) {
            size_t rowoff = (size_t)(rbase + r) * crow;
#pragma unroll
            for (int j = 0; j < 4; ++j) {
                int col = n0 + wn * 64 + j * 16 + lane15;
                C[rowoff + col] = f2bf(acc[i][j][r]);
            }
        }
    }
}

// ---------------------------------------------------------------------------
// Final 1x1 conv: out[n,o,p] = b[o] + sum_{g,c} W[o,g*32+c] * H_g[(n*32+c)*12+l][v]
// Block: one n, v-tile of 32 (=> p-tile 384), all 64 o.  H read coalesced
// (64B row segments), transposed into Hl[p][c] in LDS.
__global__ __launch_bounds__(256, 2) void final_gemm2(const float* __restrict__ x,
                                                      const short* __restrict__ H,
                                                      const float* __restrict__ W,
                                                      const float* __restrict__ bias,
                                                      float* __restrict__ out) {
    __shared__ __align__(16) short Wl[64 * 40];
    __shared__ __align__(16) short Hl[384 * 40];

    const int t  = threadIdx.x;
    const int lane = t & 63;
    const int wv   = t >> 6;
    const int lane15 = lane & 15;
    const int lq     = lane >> 4;
    const int n  = blockIdx.y;
    const int v0 = blockIdx.x * 32;
    const int p0 = v0 * 12;

    // H staging map (g>=1): wave-uniform lane4, 32 c-lanes -> clean banks
    const int hc    = t & 31;
    const int hw    = t >> 5;        // 0..7
    const int l_lo  = hw & 1;
    const int lane4 = hw >> 1;       // 0..3  (constant per wave)

    f32x4 acc[4][6] = {};

    for (int g = 0; g < 7; ++g) {
        __syncthreads();
        // stage W[:, g*32:(g+1)*32]
        {
            int o = t >> 2, c0 = (t & 3) * 8;
            const float* wp = W + (size_t)o * 224 + g * 32 + c0;
            float4 w0 = *(const float4*)wp;
            float4 w1 = *(const float4*)(wp + 4);
            short* d = &Wl[o * 40 + c0];
            d[0] = f2bf(w0.x); d[1] = f2bf(w0.y); d[2] = f2bf(w0.z); d[3] = f2bf(w0.w);
            d[4] = f2bf(w1.x); d[5] = f2bf(w1.y); d[6] = f2bf(w1.z); d[7] = f2bf(w1.w);
        }
        if (g == 0) {
            // H_0 = x itself: rows contiguous in p
            int c = t >> 3, j0 = t & 7;
            const float* src = x + ((size_t)n * 32 + c) * 12288 + p0;
#pragma unroll
            for (int it = 0; it < 12; ++it) {
                int ch = j0 + it * 8;          // 0..95
                float4 v = *(const float4*)(src + ch * 4);
                int p = ch * 4;
                Hl[(p + 0) * 40 + c] = f2bf(v.x);
                Hl[(p + 1) * 40 + c] = f2bf(v.y);
                Hl[(p + 2) * 40 + c] = f2bf(v.z);
                Hl[(p + 3) * 40 + c] = f2bf(v.w);
            }
        } else {
            // H_g row (n*32+c)*12+l, 32 v's = 64B aligned segment
            const short* base = H + (size_t)(g - 1) * 1024 + v0 + lane4 * 8;
#pragma unroll
            for (int lt = 0; lt < 6; ++lt) {
                int l = l_lo + 2 * lt;
                size_t row = ((size_t)n * 32 + hc) * 12 + l;
                s16x8 h8 = *(const s16x8*)(base + row * 6144);
#pragma unroll
                for (int i = 0; i < 8; ++i)
                    Hl[((lane4 * 8 + i) * 12 + l) * 40 + hc] = h8[i];
            }
        }
        __syncthreads();

        s16x8 af[4], bf[6];
#pragma unroll
        for (int ot = 0; ot < 4; ++ot)
            af[ot] = *(const s16x8*)&Wl[(ot * 16 + lane15) * 40 + lq * 8];
#pragma unroll
        for (int bt = 0; bt < 6; ++bt)
            bf[bt] = *(const s16x8*)&Hl[(wv * 96 + bt * 16 + lane15) * 40 + lq * 8];
#pragma unroll
        for (int ot = 0; ot < 4; ++ot)
#pragma unroll
            for (int bt = 0; bt < 6; ++bt)
                acc[ot][bt] = mfma16(af[ot], bf[bt], acc[ot][bt]);
    }

    // epilogue: row = o, col = p (coalesced across lane15)
#pragma unroll
    for (int ot = 0; ot < 4; ++ot) {
#pragma unroll
        for (int r = 0; r < 4; ++r) {
            int o = ot * 16 + lq * 4 + r;
            float bo = bias[o];
            float* op = out + ((size_t)n * 64 + o) * 12288 + p0;
#pragma unroll
            for (int bt = 0; bt < 6; ++bt) {
                int p = wv * 96 + bt * 16 + lane15;
                op[p] = acc[ot][bt][r] + bo;
            }
        }
    }
}

// ---------------------------------------------------------------------------
extern "C" void kernel_launch(void* const* d_in, const int* in_sizes, int n_in,
                              void* d_out, int out_size, void* d_ws, size_t ws_size,
                              hipStream_t stream) {
    const float* x  = (const float*)d_in[0];
    const float* a0 = (const float*)d_in[1];
    const float* a1 = (const float*)d_in[2];
    const float* a2 = (const float*)d_in[3];
    const float* W  = (const float*)d_in[4];
    const float* bs = (const float*)d_in[5];
    float* out = (float*)d_out;

    // workspace (bytes):
    //   Xg    bf16 [24576][1024]   @ 0           50,331,648
    //   Ab    bf16 [3][1024][1024] @ 50331648     6,291,456
    //   Btall bf16 [6][1024][1024] @ 56623104    12,582,912
    //   Hmv   bf16 [24576][6144]   @ 69206016   301,989,888   (ends 371,195,904)
    char* ws = (char*)d_ws;
    short* Xg    = (short*)(ws);
    short* Ab    = (short*)(ws + 50331648L);
    short* Btall = (short*)(ws + 56623104L);
    short* Hmv   = (short*)(ws + 69206016L);

    cast_x_v2<<<2048, 256, 0, stream>>>(x, Xg);
    cast_a_v2<<<dim3(32, 32, 3), 256, 0, stream>>>(a0, a1, a2, Btall, Ab);

    // (A_j^2)^T = btgemm(X=A_j^T, Bt=A_j): C[w][v] = sum_u At[w][u]*Ab[v][u]
    //           = sum_u A[u][w]*A[v][u] = (A^2)[v][w]   -> slice 2j+1
    gemm_bt<<<dim3(8, 8, 3), 256, 0, stream>>>(
        Btall, 2097152L, Ab, 1048576L, Btall + 1048576L, 2097152L, 1024);

    // all 6 diffusion outputs in one GEMM: Hmv[m][s*1024+v]
    gemm_bt<<<dim3(48, 192, 1), 256, 0, stream>>>(
        Xg, 0L, Btall, 0L, Hmv, 0L, 6144);

    final_gemm2<<<dim3(32, 64), 256, 0, stream>>>(x, Hmv, W, bs, out);
}